// Round 5
// baseline (393.058 us; speedup 1.0000x reference)
//
#include <hip/hip_runtime.h>
#include <hip/hip_bf16.h>

// Problem constants (fixed by the reference).
#define NNODES 10000
#define NEDGES 160000
#define FIN    2208
#define HDIM   512
#define NCLS   2

#define MPAD   10240     // 80 * 128
#define K1PAD  2240      // 2208 padded to multiple of 64

typedef __bf16 bf16x8 __attribute__((ext_vector_type(8)));
typedef float  f32x4  __attribute__((ext_vector_type(4)));
typedef unsigned short u16x8 __attribute__((ext_vector_type(8)));

__device__ inline unsigned short f2bf(float f) {
    union { float f; unsigned int u; } v; v.f = f;
    return (unsigned short)((v.u + 0x7FFFu + ((v.u >> 16) & 1u)) >> 16);
}
__device__ inline float bf2f(unsigned short u) {
    union { unsigned int i; float f; } v; v.i = ((unsigned int)u) << 16; return v.f;
}
// pack two fp32 into two bf16 (round-half-up ~= RNE; 3 VALU)
__device__ inline unsigned int pack2bf(float a, float b) {
    union { float f; unsigned int u; } ua, ub; ua.f = a; ub.f = b;
    return ((ub.u + 0x8000u) & 0xFFFF0000u) | ((ua.u + 0x8000u) >> 16);
}

// ---------------- prep: weight transposes + cnt init, one dispatch ----------------
// grid (14, 512): bx 0-8 -> W1t, 9-10 -> W2t, 11-12 -> W3t, 13 -> init
__global__ void k_prep(const float* __restrict__ W1, const float* __restrict__ W2,
                       const float* __restrict__ W3, unsigned short* __restrict__ W1t,
                       unsigned short* __restrict__ W2t, unsigned short* __restrict__ W3t,
                       int* __restrict__ cnt, int* __restrict__ row_cnt) {
    int n = blockIdx.y;
    int bx = blockIdx.x;
    int t = threadIdx.x;
    if (bx < 9) {
        int k = bx * 256 + t;
        if (k < K1PAD) {
            float v = (k < FIN) ? W1[(size_t)k * HDIM + n] : 0.0f;
            W1t[(size_t)n * K1PAD + k] = f2bf(v);
        }
    } else if (bx < 11) {
        int k = (bx - 9) * 256 + t;
        W2t[(size_t)n * HDIM + k] = f2bf(W2[(size_t)k * HDIM + n]);
    } else if (bx < 13) {
        int k = (bx - 11) * 256 + t;
        W3t[(size_t)n * HDIM + k] = f2bf(W3[(size_t)k * HDIM + n]);
    } else {
        int i = n * 256 + t;
        if (i < NNODES) { cnt[i] = 0; row_cnt[i] = 0; }
    }
}

__global__ void k_hist(const int* __restrict__ ei, int* __restrict__ cnt, int e) {
    int i = blockIdx.x * blockDim.x + threadIdx.x;
    if (i < e) atomicAdd(&cnt[ei[NEDGES + i]], 1);
}

// single-block scan (wave-shuffle) + dinv fold. row_ptr[0]=0, row_ptr[i+1]=incl[i]
__global__ void k_scan(const int* __restrict__ cnt, int* __restrict__ row_ptr,
                       float* __restrict__ dinv, int n) {
    __shared__ int wsum[16];
    __shared__ int s_carry;
    int tid = threadIdx.x;
    int lane = tid & 63, wid = tid >> 6;
    if (tid == 0) { s_carry = 0; row_ptr[0] = 0; }
    __syncthreads();
    for (int base = 0; base < n; base += 1024) {
        int i = base + tid;
        int deg = (i < n) ? cnt[i] : 0;
        if (i < n) dinv[i] = rsqrtf((float)deg + 1.0f);
        int v = deg;
        #pragma unroll
        for (int off = 1; off < 64; off <<= 1) {
            int t = __shfl_up(v, off);
            if (lane >= off) v += t;
        }
        if (lane == 63) wsum[wid] = v;
        __syncthreads();
        if (wid == 0) {
            int s = (lane < 16) ? wsum[lane] : 0;
            #pragma unroll
            for (int off = 1; off < 16; off <<= 1) {
                int t = __shfl_up(s, off);
                if (lane >= off) s += t;
            }
            if (lane < 16) wsum[lane] = s;
        }
        __syncthreads();
        int add = s_carry + ((wid > 0) ? wsum[wid - 1] : 0);
        if (i < n) row_ptr[i + 1] = v + add;
        __syncthreads();
        if (tid == 1023) s_carry += wsum[15];
        __syncthreads();
    }
}

__global__ void k_fill(const int* __restrict__ ei, const int* __restrict__ row_ptr,
                       int* __restrict__ row_cnt, int* __restrict__ col_src, int e) {
    int i = blockIdx.x * blockDim.x + threadIdx.x;
    if (i < e) {
        int src = ei[i];
        int dst = ei[NEDGES + i];
        int pos = row_ptr[dst] + atomicAdd(&row_cnt[dst], 1);
        col_src[pos] = src;
    }
}

// ---------------- GEMM1: fp32 x staged+converted in-kernel ----------------
// C[M,512] = bf16(x)[M,K1PAD] @ W1t[512,K1PAD]^T, bf16 out.
// Tile 128(M) x 64(N), BK=64, grid 640 XCD-grouped. A: fp32 global loads ->
// round-half-up pack -> ds_write_b128 (XOR-swizzled, same LDS layout as the
// bf16 path). B: global_load_lds width 16. Pad rows clamp to row NNODES-1
// (outputs discarded by the r<M store guard); pad k (>=FIN) stages zeros.

#define BKK 64

__global__ __launch_bounds__(256) void k_gemm1(
    const float* __restrict__ A,            // x [NNODES][FIN] fp32
    const unsigned short* __restrict__ Bt,  // W1t [512][K1PAD] bf16
    unsigned short* __restrict__ C,         // [MPAD][512] bf16
    int M) {
    __shared__ char As[128 * BKK * 2] __attribute__((aligned(16)));  // 16 KB
    __shared__ char Bs[64 * BKK * 2]  __attribute__((aligned(16)));  // 8 KB
    const int tid  = threadIdx.x;
    const int lane = tid & 63;
    const int w    = tid >> 6;
    const int wm   = w & 1, wn = w >> 1;
    const int quad = lane >> 4, lq = lane & 15;

    const int l     = blockIdx.x;           // 0..639
    const int xcd   = l & 7;
    const int q     = l >> 3;
    const int strip = (q >> 3) * 8 + xcd;
    const int bm    = strip * 128;
    const int bn    = (q & 7) * 64;

    f32x4 acc[4][2] = {};

    for (int k0 = 0; k0 < K1PAD; k0 += BKK) {
        // A: 1024 bf16 16B chunks, 4/thread; each = 8 fp32 loads + pack
        #pragma unroll
        for (int i = 0; i < 4; ++i) {
            int c = i * 256 + tid;
            int r = c >> 3;
            int g = (c & 7) ^ (r & 7);      // XOR swizzle (source-side)
            int row = bm + r;
            if (row >= NNODES) row = NNODES - 1;   // clamp; discarded at store
            int col = k0 + g * 8;
            uint4 pk = {0u, 0u, 0u, 0u};
            if (col < FIN) {                 // FIN % 8 == 0 -> whole chunk valid
                const float4* p = (const float4*)(A + (size_t)row * FIN + col);
                float4 f0 = p[0], f1 = p[1];
                pk.x = pack2bf(f0.x, f0.y);
                pk.y = pack2bf(f0.z, f0.w);
                pk.z = pack2bf(f1.x, f1.y);
                pk.w = pack2bf(f1.z, f1.w);
            }
            *(uint4*)(As + c * 16) = pk;
        }
        // B: 512 chunks, 2/thread, async
        #pragma unroll
        for (int i = 0; i < 2; ++i) {
            int c = i * 256 + tid;
            int r = c >> 3;
            int g = (c & 7) ^ (r & 7);
            const char* gpB = (const char*)Bt + ((size_t)(bn + r) * K1PAD + k0) * 2 + (g << 4);
            __builtin_amdgcn_global_load_lds(
                (const __attribute__((address_space(1))) void*)gpB,
                (__attribute__((address_space(3))) void*)(Bs + c * 16), 16, 0, 0);
        }
        __syncthreads();

        #pragma unroll
        for (int s = 0; s < 2; ++s) {
            bf16x8 af[4], bfr[2];
            int g = s * 4 + quad;
            #pragma unroll
            for (int i = 0; i < 4; ++i) {
                int r = wm * 64 + i * 16 + lq;
                af[i] = *(const bf16x8*)(As + r * 128 + ((g ^ (r & 7)) << 4));
            }
            #pragma unroll
            for (int j = 0; j < 2; ++j) {
                int n = wn * 32 + j * 16 + lq;
                bfr[j] = *(const bf16x8*)(Bs + n * 128 + ((g ^ (n & 7)) << 4));
            }
            #pragma unroll
            for (int i = 0; i < 4; ++i)
                #pragma unroll
                for (int j = 0; j < 2; ++j)
                    acc[i][j] = __builtin_amdgcn_mfma_f32_16x16x32_bf16(
                        af[i], bfr[j], acc[i][j], 0, 0, 0);
        }
        __syncthreads();
    }

    #pragma unroll
    for (int i = 0; i < 4; ++i) {
        #pragma unroll
        for (int p = 0; p < 4; ++p) {
            int r = bm + wm * 64 + i * 16 + quad * 4 + p;
            if (r < M) {
                #pragma unroll
                for (int j = 0; j < 2; ++j) {
                    int col = bn + wn * 32 + j * 16 + lq;
                    C[(size_t)r * HDIM + col] = f2bf(acc[i][j][p]);
                }
            }
        }
    }
}

// ---------------- GEMM (layers 2/3): bf16 A via global_load_lds ----------------

__global__ __launch_bounds__(256) void k_gemm_bf16(
    const unsigned short* __restrict__ A,   // [MPAD][512] bf16
    const unsigned short* __restrict__ Bt,  // [512][512] bf16 (W transposed)
    unsigned short* __restrict__ C,         // [MPAD][512] bf16
    int M, int K) {
    __shared__ char As[128 * BKK * 2] __attribute__((aligned(16)));
    __shared__ char Bs[64 * BKK * 2]  __attribute__((aligned(16)));
    const int tid  = threadIdx.x;
    const int lane = tid & 63;
    const int w    = tid >> 6;
    const int wm   = w & 1, wn = w >> 1;
    const int quad = lane >> 4, lq = lane & 15;

    const int l     = blockIdx.x;
    const int xcd   = l & 7;
    const int q     = l >> 3;
    const int strip = (q >> 3) * 8 + xcd;
    const int bm    = strip * 128;
    const int bn    = (q & 7) * 64;

    f32x4 acc[4][2] = {};

    for (int k0 = 0; k0 < K; k0 += BKK) {
        #pragma unroll
        for (int i = 0; i < 4; ++i) {
            int c = i * 256 + tid;
            int r = c >> 3;
            int g = (c & 7) ^ (r & 7);
            const char* gpA = (const char*)A + ((size_t)(bm + r) * K + k0) * 2 + (g << 4);
            __builtin_amdgcn_global_load_lds(
                (const __attribute__((address_space(1))) void*)gpA,
                (__attribute__((address_space(3))) void*)(As + c * 16), 16, 0, 0);
        }
        #pragma unroll
        for (int i = 0; i < 2; ++i) {
            int c = i * 256 + tid;
            int r = c >> 3;
            int g = (c & 7) ^ (r & 7);
            const char* gpB = (const char*)Bt + ((size_t)(bn + r) * K + k0) * 2 + (g << 4);
            __builtin_amdgcn_global_load_lds(
                (const __attribute__((address_space(1))) void*)gpB,
                (__attribute__((address_space(3))) void*)(Bs + c * 16), 16, 0, 0);
        }
        __syncthreads();

        #pragma unroll
        for (int s = 0; s < 2; ++s) {
            bf16x8 af[4], bfr[2];
            int g = s * 4 + quad;
            #pragma unroll
            for (int i = 0; i < 4; ++i) {
                int r = wm * 64 + i * 16 + lq;
                af[i] = *(const bf16x8*)(As + r * 128 + ((g ^ (r & 7)) << 4));
            }
            #pragma unroll
            for (int j = 0; j < 2; ++j) {
                int n = wn * 32 + j * 16 + lq;
                bfr[j] = *(const bf16x8*)(Bs + n * 128 + ((g ^ (n & 7)) << 4));
            }
            #pragma unroll
            for (int i = 0; i < 4; ++i)
                #pragma unroll
                for (int j = 0; j < 2; ++j)
                    acc[i][j] = __builtin_amdgcn_mfma_f32_16x16x32_bf16(
                        af[i], bfr[j], acc[i][j], 0, 0, 0);
        }
        __syncthreads();
    }

    #pragma unroll
    for (int i = 0; i < 4; ++i) {
        #pragma unroll
        for (int p = 0; p < 4; ++p) {
            int r = bm + wm * 64 + i * 16 + quad * 4 + p;
            if (r < M) {
                #pragma unroll
                for (int j = 0; j < 2; ++j) {
                    int col = bn + wn * 32 + j * 16 + lq;
                    C[(size_t)r * HDIM + col] = f2bf(acc[i][j][p]);
                }
            }
        }
    }
}

// ---------------- aggregation (layers 1/2): bf16 in, fp32 acc, bf16+relu out ----

__global__ void k_agg(const unsigned short* __restrict__ Y, const float* __restrict__ dinv,
                      const int* __restrict__ row_ptr, const int* __restrict__ col_src,
                      const float* __restrict__ bias, unsigned short* __restrict__ Hb) {
    int w = (blockIdx.x * blockDim.x + threadIdx.x) >> 6;
    int lane = threadIdx.x & 63;
    if (w >= MPAD) return;
    unsigned short* hr = Hb + (size_t)w * HDIM + lane * 8;
    if (w >= NNODES) {
        u16x8 z = {0, 0, 0, 0, 0, 0, 0, 0};
        *(u16x8*)hr = z;
        return;
    }
    float di = dinv[w];
    float sw = di * di;
    u16x8 own = *(const u16x8*)(Y + (size_t)w * HDIM + lane * 8);
    float acc[8];
    #pragma unroll
    for (int t = 0; t < 8; ++t) acc[t] = sw * bf2f(own[t]);

    int e0 = row_ptr[w], e1 = row_ptr[w + 1];
    int e = e0;
    for (; e + 4 <= e1; e += 4) {
        int s0 = col_src[e + 0], s1 = col_src[e + 1];
        int s2 = col_src[e + 2], s3 = col_src[e + 3];
        float w0 = di * dinv[s0], w1 = di * dinv[s1];
        float w2 = di * dinv[s2], w3 = di * dinv[s3];
        u16x8 v0 = *(const u16x8*)(Y + (size_t)s0 * HDIM + lane * 8);
        u16x8 v1 = *(const u16x8*)(Y + (size_t)s1 * HDIM + lane * 8);
        u16x8 v2 = *(const u16x8*)(Y + (size_t)s2 * HDIM + lane * 8);
        u16x8 v3 = *(const u16x8*)(Y + (size_t)s3 * HDIM + lane * 8);
        #pragma unroll
        for (int t = 0; t < 8; ++t) {
            acc[t] += w0 * bf2f(v0[t]);
            acc[t] += w1 * bf2f(v1[t]);
            acc[t] += w2 * bf2f(v2[t]);
            acc[t] += w3 * bf2f(v3[t]);
        }
    }
    for (; e < e1; ++e) {
        int s = col_src[e];
        float wg = di * dinv[s];
        u16x8 v = *(const u16x8*)(Y + (size_t)s * HDIM + lane * 8);
        #pragma unroll
        for (int t = 0; t < 8; ++t) acc[t] += wg * bf2f(v[t]);
    }

    float4 b0 = ((const float4*)bias)[lane * 2];
    float4 b1 = ((const float4*)bias)[lane * 2 + 1];
    acc[0] += b0.x; acc[1] += b0.y; acc[2] += b0.z; acc[3] += b0.w;
    acc[4] += b1.x; acc[5] += b1.y; acc[6] += b1.z; acc[7] += b1.w;
    u16x8 o;
    #pragma unroll
    for (int t = 0; t < 8; ++t) o[t] = f2bf(fmaxf(acc[t], 0.0f));
    *(u16x8*)hr = o;
}

// ---------------- agg3 + relu + layer-4 GEMM fused: H stays in registers ------

__global__ void k_agg_g4(const unsigned short* __restrict__ Y, const float* __restrict__ dinv,
                         const int* __restrict__ row_ptr, const int* __restrict__ col_src,
                         const float* __restrict__ b3, const float* __restrict__ W4,
                         float* __restrict__ Y4) {
    int w = (blockIdx.x * blockDim.x + threadIdx.x) >> 6;
    int lane = threadIdx.x & 63;
    if (w >= NNODES) return;
    float di = dinv[w];
    float sw = di * di;
    u16x8 own = *(const u16x8*)(Y + (size_t)w * HDIM + lane * 8);
    float acc[8];
    #pragma unroll
    for (int t = 0; t < 8; ++t) acc[t] = sw * bf2f(own[t]);

    int e0 = row_ptr[w], e1 = row_ptr[w + 1];
    int e = e0;
    for (; e + 4 <= e1; e += 4) {
        int s0 = col_src[e + 0], s1 = col_src[e + 1];
        int s2 = col_src[e + 2], s3 = col_src[e + 3];
        float w0 = di * dinv[s0], w1 = di * dinv[s1];
        float w2 = di * dinv[s2], w3 = di * dinv[s3];
        u16x8 v0 = *(const u16x8*)(Y + (size_t)s0 * HDIM + lane * 8);
        u16x8 v1 = *(const u16x8*)(Y + (size_t)s1 * HDIM + lane * 8);
        u16x8 v2 = *(const u16x8*)(Y + (size_t)s2 * HDIM + lane * 8);
        u16x8 v3 = *(const u16x8*)(Y + (size_t)s3 * HDIM + lane * 8);
        #pragma unroll
        for (int t = 0; t < 8; ++t) {
            acc[t] += w0 * bf2f(v0[t]);
            acc[t] += w1 * bf2f(v1[t]);
            acc[t] += w2 * bf2f(v2[t]);
            acc[t] += w3 * bf2f(v3[t]);
        }
    }
    for (; e < e1; ++e) {
        int s = col_src[e];
        float wg = di * dinv[s];
        u16x8 v = *(const u16x8*)(Y + (size_t)s * HDIM + lane * 8);
        #pragma unroll
        for (int t = 0; t < 8; ++t) acc[t] += wg * bf2f(v[t]);
    }

    float4 b0 = ((const float4*)b3)[lane * 2];
    float4 b1 = ((const float4*)b3)[lane * 2 + 1];
    acc[0] += b0.x; acc[1] += b0.y; acc[2] += b0.z; acc[3] += b0.w;
    acc[4] += b1.x; acc[5] += b1.y; acc[6] += b1.z; acc[7] += b1.w;
    #pragma unroll
    for (int t = 0; t < 8; ++t) acc[t] = fmaxf(acc[t], 0.0f);

    // dot with W4 [512][2] fp32; lane owns k = lane*8 .. lane*8+7
    const float4* wf = (const float4*)W4;
    float4 w0 = wf[lane * 4 + 0];
    float4 w1 = wf[lane * 4 + 1];
    float4 w2 = wf[lane * 4 + 2];
    float4 w3 = wf[lane * 4 + 3];
    float z0 = acc[0]*w0.x + acc[1]*w0.z + acc[2]*w1.x + acc[3]*w1.z
             + acc[4]*w2.x + acc[5]*w2.z + acc[6]*w3.x + acc[7]*w3.z;
    float z1 = acc[0]*w0.y + acc[1]*w0.w + acc[2]*w1.y + acc[3]*w1.w
             + acc[4]*w2.y + acc[5]*w2.w + acc[6]*w3.y + acc[7]*w3.w;
    #pragma unroll
    for (int off = 32; off > 0; off >>= 1) {
        z0 += __shfl_down(z0, off);
        z1 += __shfl_down(z1, off);
    }
    if (lane == 0) {
        Y4[2 * w] = z0;
        Y4[2 * w + 1] = z1;
    }
}

// ---------------- layer-4 aggregation + bias + log_softmax ----------------

__global__ void k_final(const float* __restrict__ Y4, const float* __restrict__ dinv,
                        const int* __restrict__ row_ptr, const int* __restrict__ col_src,
                        const float* __restrict__ b4, float* __restrict__ out, int n) {
    int i = blockIdx.x * blockDim.x + threadIdx.x;
    if (i >= n) return;
    float di = dinv[i];
    float sw = di * di;
    float z0 = sw * Y4[2 * i];
    float z1 = sw * Y4[2 * i + 1];
    int e0 = row_ptr[i], e1 = row_ptr[i + 1];
    for (int e = e0; e < e1; ++e) {
        int s = col_src[e];
        float wgt = di * dinv[s];
        z0 += wgt * Y4[2 * s];
        z1 += wgt * Y4[2 * s + 1];
    }
    z0 += b4[0];
    z1 += b4[1];
    float m = fmaxf(z0, z1);
    float l = m + logf(expf(z0 - m) + expf(z1 - m));
    out[2 * i] = z0 - l;
    out[2 * i + 1] = z1 - l;
}

// ---------------- launch ----------------

extern "C" void kernel_launch(void* const* d_in, const int* in_sizes, int n_in,
                              void* d_out, int out_size, void* d_ws, size_t ws_size,
                              hipStream_t stream) {
    const float* x  = (const float*)d_in[0];
    const int*   ei = (const int*)d_in[1];
    const float* W1 = (const float*)d_in[3];
    const float* b1 = (const float*)d_in[4];
    const float* W2 = (const float*)d_in[5];
    const float* b2 = (const float*)d_in[6];
    const float* W3 = (const float*)d_in[7];
    const float* b3 = (const float*)d_in[8];
    const float* W4 = (const float*)d_in[9];
    const float* b4 = (const float*)d_in[10];
    float* out = (float*)d_out;

    char* ws = (char*)d_ws;
    // workspace layout (bytes, 256-aligned)
    float*          dinv    = (float*)(ws + 0);                  // 40,000
    int*            cnt     = (int*)  (ws + 40960);
    int*            row_cnt = (int*)  (ws + 81920);
    int*            row_ptr = (int*)  (ws + 122880);             // 40,004
    int*            col_src = (int*)  (ws + 163840);             // 640,000
    float*          Y4      = (float*)(ws + 803840);             // 80,000
    unsigned short* W1t     = (unsigned short*)(ws + 884224);    // 512*K1PAD*2 = 2,293,760
    unsigned short* W2t     = (unsigned short*)(ws + 3177984);   // 524,288
    unsigned short* W3t     = (unsigned short*)(ws + 3702272);   // 524,288
    unsigned short* Yb      = (unsigned short*)(ws + 4226560);   // MPAD*512*2 = 10,485,760
    unsigned short* Hb      = (unsigned short*)(ws + 14712320);  // 10,485,760
    // total: 25,198,080 bytes
    if (ws_size < 25198080) return;

    // prep: weight transposes + cnt init (one dispatch), then graph CSR
    k_prep<<<dim3(14, HDIM), 256, 0, stream>>>(W1, W2, W3, W1t, W2t, W3t, cnt, row_cnt);
    k_hist<<<625, 256, 0, stream>>>(ei, cnt, NEDGES);
    k_scan<<<1, 1024, 0, stream>>>(cnt, row_ptr, dinv, NNODES);
    k_fill<<<625, 256, 0, stream>>>(ei, row_ptr, row_cnt, col_src, NEDGES);

    const int ggrid = (MPAD / 128) * 8;   // 640 linear blocks, XCD-grouped decode
    const int agrid = (MPAD * 64) / 256;  // one wave per (padded) node

    // layer 1 (conversion fused into GEMM1's A-staging)
    k_gemm1<<<ggrid, 256, 0, stream>>>(x, W1t, Yb, NNODES);
    k_agg<<<agrid, 256, 0, stream>>>(Yb, dinv, row_ptr, col_src, b1, Hb);
    // layer 2
    k_gemm_bf16<<<ggrid, 256, 0, stream>>>(Hb, W2t, Yb, NNODES, HDIM);
    k_agg<<<agrid, 256, 0, stream>>>(Yb, dinv, row_ptr, col_src, b2, Hb);
    // layer 3 + layer-4 GEMM fused (H row stays in registers)
    k_gemm_bf16<<<ggrid, 256, 0, stream>>>(Hb, W3t, Yb, NNODES, HDIM);
    k_agg_g4<<<(NNODES * 64) / 256, 256, 0, stream>>>(Yb, dinv, row_ptr, col_src, b3, W4, Y4);
    // layer-4 aggregation + log_softmax
    k_final<<<40, 256, 0, stream>>>(Y4, dinv, row_ptr, col_src, b4, out, NNODES);
}

// Round 6
// 337.157 us; speedup vs baseline: 1.1658x; 1.1658x over previous
//
#include <hip/hip_runtime.h>
#include <hip/hip_bf16.h>

// Problem constants (fixed by the reference).
#define NNODES 10000
#define NEDGES 160000
#define FIN    2208
#define HDIM   512
#define NCLS   2

#define MPAD   10240     // 80 * 128
#define K1PAD  2240      // 2208 padded to multiple of 64

typedef __bf16 bf16x8 __attribute__((ext_vector_type(8)));
typedef float  f32x4  __attribute__((ext_vector_type(4)));
typedef unsigned short u16x8 __attribute__((ext_vector_type(8)));

__device__ inline unsigned short f2bf(float f) {
    union { float f; unsigned int u; } v; v.f = f;
    return (unsigned short)((v.u + 0x7FFFu + ((v.u >> 16) & 1u)) >> 16);
}
__device__ inline float bf2f(unsigned short u) {
    union { unsigned int i; float f; } v; v.i = ((unsigned int)u) << 16; return v.f;
}

// ---------------- prep: weight transposes + cnt init, one dispatch ----------------
// grid (14, 512): bx 0-8 -> W1t, 9-10 -> W2t, 11-12 -> W3t, 13 -> init
__global__ void k_prep(const float* __restrict__ W1, const float* __restrict__ W2,
                       const float* __restrict__ W3, unsigned short* __restrict__ W1t,
                       unsigned short* __restrict__ W2t, unsigned short* __restrict__ W3t,
                       int* __restrict__ cnt, int* __restrict__ row_cnt) {
    int n = blockIdx.y;
    int bx = blockIdx.x;
    int t = threadIdx.x;
    if (bx < 9) {
        int k = bx * 256 + t;
        if (k < K1PAD) {
            float v = (k < FIN) ? W1[(size_t)k * HDIM + n] : 0.0f;
            W1t[(size_t)n * K1PAD + k] = f2bf(v);
        }
    } else if (bx < 11) {
        int k = (bx - 9) * 256 + t;
        W2t[(size_t)n * HDIM + k] = f2bf(W2[(size_t)k * HDIM + n]);
    } else if (bx < 13) {
        int k = (bx - 11) * 256 + t;
        W3t[(size_t)n * HDIM + k] = f2bf(W3[(size_t)k * HDIM + n]);
    } else {
        int i = n * 256 + t;
        if (i < NNODES) { cnt[i] = 0; row_cnt[i] = 0; }
    }
}

__global__ void k_hist(const int* __restrict__ ei, int* __restrict__ cnt, int e) {
    int i = blockIdx.x * blockDim.x + threadIdx.x;
    if (i < e) atomicAdd(&cnt[ei[NEDGES + i]], 1);
}

// single-block scan (wave-shuffle) + dinv fold. row_ptr[0]=0, row_ptr[i+1]=incl[i]
__global__ void k_scan(const int* __restrict__ cnt, int* __restrict__ row_ptr,
                       float* __restrict__ dinv, int n) {
    __shared__ int wsum[16];
    __shared__ int s_carry;
    int tid = threadIdx.x;
    int lane = tid & 63, wid = tid >> 6;
    if (tid == 0) { s_carry = 0; row_ptr[0] = 0; }
    __syncthreads();
    for (int base = 0; base < n; base += 1024) {
        int i = base + tid;
        int deg = (i < n) ? cnt[i] : 0;
        if (i < n) dinv[i] = rsqrtf((float)deg + 1.0f);
        int v = deg;
        #pragma unroll
        for (int off = 1; off < 64; off <<= 1) {
            int t = __shfl_up(v, off);
            if (lane >= off) v += t;
        }
        if (lane == 63) wsum[wid] = v;
        __syncthreads();
        if (wid == 0) {
            int s = (lane < 16) ? wsum[lane] : 0;
            #pragma unroll
            for (int off = 1; off < 16; off <<= 1) {
                int t = __shfl_up(s, off);
                if (lane >= off) s += t;
            }
            if (lane < 16) wsum[lane] = s;
        }
        __syncthreads();
        int add = s_carry + ((wid > 0) ? wsum[wid - 1] : 0);
        if (i < n) row_ptr[i + 1] = v + add;
        __syncthreads();
        if (tid == 1023) s_carry += wsum[15];
        __syncthreads();
    }
}

__global__ void k_fill(const int* __restrict__ ei, const int* __restrict__ row_ptr,
                       int* __restrict__ row_cnt, int* __restrict__ col_src, int e) {
    int i = blockIdx.x * blockDim.x + threadIdx.x;
    if (i < e) {
        int src = ei[i];
        int dst = ei[NEDGES + i];
        int pos = row_ptr[dst] + atomicAdd(&row_cnt[dst], 1);
        col_src[pos] = src;
    }
}

// ---------------- converter: x fp32 -> xb bf16 [MPAD][K1PAD] ----------------
// Separate streaming pass (R5 post-mortem: fusing this into GEMM1's staging
// loses the async global_load_lds path and doubles LLC A-traffic -> 4x slower).
__global__ void k_cvt_x(const float* __restrict__ x, unsigned short* __restrict__ xb) {
    int row = blockIdx.x;
    int t = threadIdx.x;
    unsigned short* orow = xb + (size_t)row * K1PAD;
    u16x8 z = {0, 0, 0, 0, 0, 0, 0, 0};
    if (row >= NNODES) {
        for (int c = t; c < K1PAD / 8; c += 256) *(u16x8*)(orow + c * 8) = z;
        return;
    }
    const float* irow = x + (size_t)row * FIN;
    for (int c = t; c < K1PAD / 8; c += 256) {
        int col = c * 8;
        u16x8 o = z;
        if (col + 8 <= FIN) {   // FIN % 8 == 0 -> clean boundary
            float4 f0 = *(const float4*)(irow + col);
            float4 f1 = *(const float4*)(irow + col + 4);
            o[0] = f2bf(f0.x); o[1] = f2bf(f0.y); o[2] = f2bf(f0.z); o[3] = f2bf(f0.w);
            o[4] = f2bf(f1.x); o[5] = f2bf(f1.y); o[6] = f2bf(f1.z); o[7] = f2bf(f1.w);
        }
        *(u16x8*)(orow + col) = o;
    }
}

// ---------------- bf16 MFMA GEMM: C[M,512] = A[M,K] @ Bt[512,K]^T, bf16 out ----
// Tile 128(M) x 64(N), BK=64, grid 640 linear (2.5 blocks/CU). 4 waves 2x2;
// wave tile 64x32. XOR-swizzled LDS, global_load_lds width 16. XCD-grouped
// decode keeps one strip's 8 n-tiles on one XCD (A strip reused from L2).

#define BKK 64

__global__ __launch_bounds__(256) void k_gemm_bf16(
    const unsigned short* __restrict__ A,   // [MPAD][K] bf16
    const unsigned short* __restrict__ Bt,  // [512][K] bf16 (W transposed)
    unsigned short* __restrict__ C,         // [MPAD][512] bf16
    int M, int K) {
    __shared__ char As[128 * BKK * 2] __attribute__((aligned(16)));  // 16 KB
    __shared__ char Bs[64 * BKK * 2]  __attribute__((aligned(16)));  // 8 KB
    const int tid  = threadIdx.x;
    const int lane = tid & 63;
    const int w    = tid >> 6;
    const int wm   = w & 1, wn = w >> 1;
    const int quad = lane >> 4, lq = lane & 15;

    const int l     = blockIdx.x;           // 0..639
    const int xcd   = l & 7;
    const int q     = l >> 3;
    const int strip = (q >> 3) * 8 + xcd;
    const int bm    = strip * 128;
    const int bn    = (q & 7) * 64;

    f32x4 acc[4][2] = {};

    for (int k0 = 0; k0 < K; k0 += BKK) {
        #pragma unroll
        for (int i = 0; i < 4; ++i) {
            int c = i * 256 + tid;
            int r = c >> 3;
            int g = (c & 7) ^ (r & 7);      // XOR swizzle (source-side)
            const char* gpA = (const char*)A + ((size_t)(bm + r) * K + k0) * 2 + (g << 4);
            __builtin_amdgcn_global_load_lds(
                (const __attribute__((address_space(1))) void*)gpA,
                (__attribute__((address_space(3))) void*)(As + c * 16), 16, 0, 0);
        }
        #pragma unroll
        for (int i = 0; i < 2; ++i) {
            int c = i * 256 + tid;
            int r = c >> 3;
            int g = (c & 7) ^ (r & 7);
            const char* gpB = (const char*)Bt + ((size_t)(bn + r) * K + k0) * 2 + (g << 4);
            __builtin_amdgcn_global_load_lds(
                (const __attribute__((address_space(1))) void*)gpB,
                (__attribute__((address_space(3))) void*)(Bs + c * 16), 16, 0, 0);
        }
        __syncthreads();

        #pragma unroll
        for (int s = 0; s < 2; ++s) {
            bf16x8 af[4], bfr[2];
            int g = s * 4 + quad;
            #pragma unroll
            for (int i = 0; i < 4; ++i) {
                int r = wm * 64 + i * 16 + lq;
                af[i] = *(const bf16x8*)(As + r * 128 + ((g ^ (r & 7)) << 4));
            }
            #pragma unroll
            for (int j = 0; j < 2; ++j) {
                int n = wn * 32 + j * 16 + lq;
                bfr[j] = *(const bf16x8*)(Bs + n * 128 + ((g ^ (n & 7)) << 4));
            }
            #pragma unroll
            for (int i = 0; i < 4; ++i)
                #pragma unroll
                for (int j = 0; j < 2; ++j)
                    acc[i][j] = __builtin_amdgcn_mfma_f32_16x16x32_bf16(
                        af[i], bfr[j], acc[i][j], 0, 0, 0);
        }
        __syncthreads();
    }

    // C/D layout: col = lane&15, row = quad*4 + reg
    #pragma unroll
    for (int i = 0; i < 4; ++i) {
        #pragma unroll
        for (int p = 0; p < 4; ++p) {
            int r = bm + wm * 64 + i * 16 + quad * 4 + p;
            if (r < M) {
                #pragma unroll
                for (int j = 0; j < 2; ++j) {
                    int col = bn + wn * 32 + j * 16 + lq;
                    C[(size_t)r * HDIM + col] = f2bf(acc[i][j][p]);
                }
            }
        }
    }
}

// ---------------- aggregation (layers 1/2): bf16 in, fp32 acc, bf16+relu out ----

__global__ void k_agg(const unsigned short* __restrict__ Y, const float* __restrict__ dinv,
                      const int* __restrict__ row_ptr, const int* __restrict__ col_src,
                      const float* __restrict__ bias, unsigned short* __restrict__ Hb) {
    int w = (blockIdx.x * blockDim.x + threadIdx.x) >> 6;
    int lane = threadIdx.x & 63;
    if (w >= MPAD) return;
    unsigned short* hr = Hb + (size_t)w * HDIM + lane * 8;
    if (w >= NNODES) {
        u16x8 z = {0, 0, 0, 0, 0, 0, 0, 0};
        *(u16x8*)hr = z;
        return;
    }
    float di = dinv[w];
    float sw = di * di;
    u16x8 own = *(const u16x8*)(Y + (size_t)w * HDIM + lane * 8);
    float acc[8];
    #pragma unroll
    for (int t = 0; t < 8; ++t) acc[t] = sw * bf2f(own[t]);

    int e0 = row_ptr[w], e1 = row_ptr[w + 1];
    int e = e0;
    for (; e + 4 <= e1; e += 4) {
        int s0 = col_src[e + 0], s1 = col_src[e + 1];
        int s2 = col_src[e + 2], s3 = col_src[e + 3];
        float w0 = di * dinv[s0], w1 = di * dinv[s1];
        float w2 = di * dinv[s2], w3 = di * dinv[s3];
        u16x8 v0 = *(const u16x8*)(Y + (size_t)s0 * HDIM + lane * 8);
        u16x8 v1 = *(const u16x8*)(Y + (size_t)s1 * HDIM + lane * 8);
        u16x8 v2 = *(const u16x8*)(Y + (size_t)s2 * HDIM + lane * 8);
        u16x8 v3 = *(const u16x8*)(Y + (size_t)s3 * HDIM + lane * 8);
        #pragma unroll
        for (int t = 0; t < 8; ++t) {
            acc[t] += w0 * bf2f(v0[t]);
            acc[t] += w1 * bf2f(v1[t]);
            acc[t] += w2 * bf2f(v2[t]);
            acc[t] += w3 * bf2f(v3[t]);
        }
    }
    for (; e < e1; ++e) {
        int s = col_src[e];
        float wg = di * dinv[s];
        u16x8 v = *(const u16x8*)(Y + (size_t)s * HDIM + lane * 8);
        #pragma unroll
        for (int t = 0; t < 8; ++t) acc[t] += wg * bf2f(v[t]);
    }

    float4 b0 = ((const float4*)bias)[lane * 2];
    float4 b1 = ((const float4*)bias)[lane * 2 + 1];
    acc[0] += b0.x; acc[1] += b0.y; acc[2] += b0.z; acc[3] += b0.w;
    acc[4] += b1.x; acc[5] += b1.y; acc[6] += b1.z; acc[7] += b1.w;
    u16x8 o;
    #pragma unroll
    for (int t = 0; t < 8; ++t) o[t] = f2bf(fmaxf(acc[t], 0.0f));
    *(u16x8*)hr = o;
}

// ---------------- agg3 + relu + layer-4 GEMM fused: H stays in registers ------

__global__ void k_agg_g4(const unsigned short* __restrict__ Y, const float* __restrict__ dinv,
                         const int* __restrict__ row_ptr, const int* __restrict__ col_src,
                         const float* __restrict__ b3, const float* __restrict__ W4,
                         float* __restrict__ Y4) {
    int w = (blockIdx.x * blockDim.x + threadIdx.x) >> 6;
    int lane = threadIdx.x & 63;
    if (w >= NNODES) return;
    float di = dinv[w];
    float sw = di * di;
    u16x8 own = *(const u16x8*)(Y + (size_t)w * HDIM + lane * 8);
    float acc[8];
    #pragma unroll
    for (int t = 0; t < 8; ++t) acc[t] = sw * bf2f(own[t]);

    int e0 = row_ptr[w], e1 = row_ptr[w + 1];
    int e = e0;
    for (; e + 4 <= e1; e += 4) {
        int s0 = col_src[e + 0], s1 = col_src[e + 1];
        int s2 = col_src[e + 2], s3 = col_src[e + 3];
        float w0 = di * dinv[s0], w1 = di * dinv[s1];
        float w2 = di * dinv[s2], w3 = di * dinv[s3];
        u16x8 v0 = *(const u16x8*)(Y + (size_t)s0 * HDIM + lane * 8);
        u16x8 v1 = *(const u16x8*)(Y + (size_t)s1 * HDIM + lane * 8);
        u16x8 v2 = *(const u16x8*)(Y + (size_t)s2 * HDIM + lane * 8);
        u16x8 v3 = *(const u16x8*)(Y + (size_t)s3 * HDIM + lane * 8);
        #pragma unroll
        for (int t = 0; t < 8; ++t) {
            acc[t] += w0 * bf2f(v0[t]);
            acc[t] += w1 * bf2f(v1[t]);
            acc[t] += w2 * bf2f(v2[t]);
            acc[t] += w3 * bf2f(v3[t]);
        }
    }
    for (; e < e1; ++e) {
        int s = col_src[e];
        float wg = di * dinv[s];
        u16x8 v = *(const u16x8*)(Y + (size_t)s * HDIM + lane * 8);
        #pragma unroll
        for (int t = 0; t < 8; ++t) acc[t] += wg * bf2f(v[t]);
    }

    float4 b0 = ((const float4*)b3)[lane * 2];
    float4 b1 = ((const float4*)b3)[lane * 2 + 1];
    acc[0] += b0.x; acc[1] += b0.y; acc[2] += b0.z; acc[3] += b0.w;
    acc[4] += b1.x; acc[5] += b1.y; acc[6] += b1.z; acc[7] += b1.w;
    #pragma unroll
    for (int t = 0; t < 8; ++t) acc[t] = fmaxf(acc[t], 0.0f);

    // dot with W4 [512][2] fp32; lane owns k = lane*8 .. lane*8+7
    const float4* wf = (const float4*)W4;
    float4 w0 = wf[lane * 4 + 0];
    float4 w1 = wf[lane * 4 + 1];
    float4 w2 = wf[lane * 4 + 2];
    float4 w3 = wf[lane * 4 + 3];
    float z0 = acc[0]*w0.x + acc[1]*w0.z + acc[2]*w1.x + acc[3]*w1.z
             + acc[4]*w2.x + acc[5]*w2.z + acc[6]*w3.x + acc[7]*w3.z;
    float z1 = acc[0]*w0.y + acc[1]*w0.w + acc[2]*w1.y + acc[3]*w1.w
             + acc[4]*w2.y + acc[5]*w2.w + acc[6]*w3.y + acc[7]*w3.w;
    #pragma unroll
    for (int off = 32; off > 0; off >>= 1) {
        z0 += __shfl_down(z0, off);
        z1 += __shfl_down(z1, off);
    }
    if (lane == 0) {
        Y4[2 * w] = z0;
        Y4[2 * w + 1] = z1;
    }
}

// ---------------- layer-4 aggregation + bias + log_softmax ----------------

__global__ void k_final(const float* __restrict__ Y4, const float* __restrict__ dinv,
                        const int* __restrict__ row_ptr, const int* __restrict__ col_src,
                        const float* __restrict__ b4, float* __restrict__ out, int n) {
    int i = blockIdx.x * blockDim.x + threadIdx.x;
    if (i >= n) return;
    float di = dinv[i];
    float sw = di * di;
    float z0 = sw * Y4[2 * i];
    float z1 = sw * Y4[2 * i + 1];
    int e0 = row_ptr[i], e1 = row_ptr[i + 1];
    for (int e = e0; e < e1; ++e) {
        int s = col_src[e];
        float wgt = di * dinv[s];
        z0 += wgt * Y4[2 * s];
        z1 += wgt * Y4[2 * s + 1];
    }
    z0 += b4[0];
    z1 += b4[1];
    float m = fmaxf(z0, z1);
    float l = m + logf(expf(z0 - m) + expf(z1 - m));
    out[2 * i] = z0 - l;
    out[2 * i + 1] = z1 - l;
}

// ---------------- launch ----------------

extern "C" void kernel_launch(void* const* d_in, const int* in_sizes, int n_in,
                              void* d_out, int out_size, void* d_ws, size_t ws_size,
                              hipStream_t stream) {
    const float* x  = (const float*)d_in[0];
    const int*   ei = (const int*)d_in[1];
    const float* W1 = (const float*)d_in[3];
    const float* b1 = (const float*)d_in[4];
    const float* W2 = (const float*)d_in[5];
    const float* b2 = (const float*)d_in[6];
    const float* W3 = (const float*)d_in[7];
    const float* b3 = (const float*)d_in[8];
    const float* W4 = (const float*)d_in[9];
    const float* b4 = (const float*)d_in[10];
    float* out = (float*)d_out;

    char* ws = (char*)d_ws;
    // workspace layout (bytes, 256-aligned)
    float*          dinv    = (float*)(ws + 0);                  // 40,000
    int*            cnt     = (int*)  (ws + 40960);
    int*            row_cnt = (int*)  (ws + 81920);
    int*            row_ptr = (int*)  (ws + 122880);             // 40,004
    int*            col_src = (int*)  (ws + 163840);             // 640,000
    float*          Y4      = (float*)(ws + 803840);             // 80,000
    unsigned short* xb      = (unsigned short*)(ws + 884224);    // MPAD*K1PAD*2 = 45,875,200
    unsigned short* W1t     = (unsigned short*)(ws + 46759424);  // 2,293,760
    unsigned short* W2t     = (unsigned short*)(ws + 49053184);  // 524,288
    unsigned short* W3t     = (unsigned short*)(ws + 49577472);  // 524,288
    unsigned short* Yb      = (unsigned short*)(ws + 50101760);  // MPAD*512*2 = 10,485,760
    unsigned short* Hb      = (unsigned short*)(ws + 60587520);  // 10,485,760
    // total: 71,073,280 bytes
    if (ws_size < 71073280) return;

    // prep: weight transposes + cnt init (one dispatch), then graph CSR
    k_prep<<<dim3(14, HDIM), 256, 0, stream>>>(W1, W2, W3, W1t, W2t, W3t, cnt, row_cnt);
    k_hist<<<625, 256, 0, stream>>>(ei, cnt, NEDGES);
    k_scan<<<1, 1024, 0, stream>>>(cnt, row_ptr, dinv, NNODES);
    k_fill<<<625, 256, 0, stream>>>(ei, row_ptr, row_cnt, col_src, NEDGES);

    // x -> bf16 (separate streaming pass; do NOT fuse into GEMM1 - see R5 note)
    k_cvt_x<<<MPAD, 256, 0, stream>>>(x, xb);

    const int ggrid = (MPAD / 128) * 8;   // 640 linear blocks, XCD-grouped decode
    const int agrid = (MPAD * 64) / 256;  // one wave per (padded) node

    // layer 1
    k_gemm_bf16<<<ggrid, 256, 0, stream>>>(xb, W1t, Yb, NNODES, K1PAD);
    k_agg<<<agrid, 256, 0, stream>>>(Yb, dinv, row_ptr, col_src, b1, Hb);
    // layer 2
    k_gemm_bf16<<<ggrid, 256, 0, stream>>>(Hb, W2t, Yb, NNODES, HDIM);
    k_agg<<<agrid, 256, 0, stream>>>(Yb, dinv, row_ptr, col_src, b2, Hb);
    // layer 3 + layer-4 GEMM fused (H row stays in registers)
    k_gemm_bf16<<<ggrid, 256, 0, stream>>>(Hb, W3t, Yb, NNODES, HDIM);
    k_agg_g4<<<(NNODES * 64) / 256, 256, 0, stream>>>(Yb, dinv, row_ptr, col_src, b3, W4, Y4);
    // layer-4 aggregation + log_softmax
    k_final<<<40, 256, 0, stream>>>(Y4, dinv, row_ptr, col_src, b4, out, NNODES);
}

// Round 7
// 327.432 us; speedup vs baseline: 1.2004x; 1.0297x over previous
//
#include <hip/hip_runtime.h>
#include <hip/hip_bf16.h>

// Problem constants (fixed by the reference).
#define NNODES 10000
#define NEDGES 160000
#define FIN    2208
#define HDIM   512
#define NCLS   2

#define MPAD   10240     // 80 * 128
#define K1PAD  2240      // 2208 padded to multiple of 64

typedef __bf16 bf16x8 __attribute__((ext_vector_type(8)));
typedef float  f32x4  __attribute__((ext_vector_type(4)));
typedef unsigned short u16x8 __attribute__((ext_vector_type(8)));

__device__ inline unsigned short f2bf(float f) {
    union { float f; unsigned int u; } v; v.f = f;
    return (unsigned short)((v.u + 0x7FFFu + ((v.u >> 16) & 1u)) >> 16);
}
__device__ inline float bf2f(unsigned short u) {
    union { unsigned int i; float f; } v; v.i = ((unsigned int)u) << 16; return v.f;
}

// ---------------- dispatch 1: weight transposes + cnt init ----------------
// grid (14, 512): bx 0-8 -> W1t, 9-10 -> W2t, 11-12 -> W3t, 13 -> init
__global__ void k_prep(const float* __restrict__ W1, const float* __restrict__ W2,
                       const float* __restrict__ W3, unsigned short* __restrict__ W1t,
                       unsigned short* __restrict__ W2t, unsigned short* __restrict__ W3t,
                       int* __restrict__ cnt, int* __restrict__ row_cnt) {
    int n = blockIdx.y;
    int bx = blockIdx.x;
    int t = threadIdx.x;
    if (bx < 9) {
        int k = bx * 256 + t;
        if (k < K1PAD) {
            float v = (k < FIN) ? W1[(size_t)k * HDIM + n] : 0.0f;
            W1t[(size_t)n * K1PAD + k] = f2bf(v);
        }
    } else if (bx < 11) {
        int k = (bx - 9) * 256 + t;
        W2t[(size_t)n * HDIM + k] = f2bf(W2[(size_t)k * HDIM + n]);
    } else if (bx < 13) {
        int k = (bx - 11) * 256 + t;
        W3t[(size_t)n * HDIM + k] = f2bf(W3[(size_t)k * HDIM + n]);
    } else {
        int i = n * 256 + t;
        if (i < NNODES) { cnt[i] = 0; row_cnt[i] = 0; }
    }
}

// ---------------- dispatch 2: x->bf16 convert (10240 blocks) + degree hist (625) --
// Independent work merged so the tiny atomic histogram hides under the
// bandwidth-bound convert. (R5 lesson: convert must NOT fuse into GEMM1's
// LDS staging; a separate streaming pass keeps the async DMA path.)
__global__ void k_cvt_hist(const float* __restrict__ x, unsigned short* __restrict__ xb,
                           const int* __restrict__ ei, int* __restrict__ cnt) {
    int bx = blockIdx.x;
    int t = threadIdx.x;
    if (bx >= MPAD) {                      // histogram part
        int i = (bx - MPAD) * 256 + t;
        if (i < NEDGES) atomicAdd(&cnt[ei[NEDGES + i]], 1);
        return;
    }
    int row = bx;                          // convert part
    unsigned short* orow = xb + (size_t)row * K1PAD;
    u16x8 z = {0, 0, 0, 0, 0, 0, 0, 0};
    if (row >= NNODES) {
        for (int c = t; c < K1PAD / 8; c += 256) *(u16x8*)(orow + c * 8) = z;
        return;
    }
    const float* irow = x + (size_t)row * FIN;
    for (int c = t; c < K1PAD / 8; c += 256) {
        int col = c * 8;
        u16x8 o = z;
        if (col + 8 <= FIN) {   // FIN % 8 == 0 -> clean boundary
            float4 f0 = *(const float4*)(irow + col);
            float4 f1 = *(const float4*)(irow + col + 4);
            o[0] = f2bf(f0.x); o[1] = f2bf(f0.y); o[2] = f2bf(f0.z); o[3] = f2bf(f0.w);
            o[4] = f2bf(f1.x); o[5] = f2bf(f1.y); o[6] = f2bf(f1.z); o[7] = f2bf(f1.w);
        }
        *(u16x8*)(orow + col) = o;
    }
}

// ---------------- dispatch 3: single-block scan + dinv ----------------
__global__ void k_scan(const int* __restrict__ cnt, int* __restrict__ row_ptr,
                       float* __restrict__ dinv, int n) {
    __shared__ int wsum[16];
    __shared__ int s_carry;
    int tid = threadIdx.x;
    int lane = tid & 63, wid = tid >> 6;
    if (tid == 0) { s_carry = 0; row_ptr[0] = 0; }
    __syncthreads();
    for (int base = 0; base < n; base += 1024) {
        int i = base + tid;
        int deg = (i < n) ? cnt[i] : 0;
        if (i < n) dinv[i] = rsqrtf((float)deg + 1.0f);
        int v = deg;
        #pragma unroll
        for (int off = 1; off < 64; off <<= 1) {
            int t = __shfl_up(v, off);
            if (lane >= off) v += t;
        }
        if (lane == 63) wsum[wid] = v;
        __syncthreads();
        if (wid == 0) {
            int s = (lane < 16) ? wsum[lane] : 0;
            #pragma unroll
            for (int off = 1; off < 16; off <<= 1) {
                int t = __shfl_up(s, off);
                if (lane >= off) s += t;
            }
            if (lane < 16) wsum[lane] = s;
        }
        __syncthreads();
        int add = s_carry + ((wid > 0) ? wsum[wid - 1] : 0);
        if (i < n) row_ptr[i + 1] = v + add;
        __syncthreads();
        if (tid == 1023) s_carry += wsum[15];
        __syncthreads();
    }
}

// ---------------- bf16 MFMA GEMM body (shared by layers 1-3) ----------------
// C[M,512] = A[M,K] @ Bt[512,K]^T, bf16 out. Tile 128(M) x 64(N), BK=64,
// 640 blocks (2.5/CU). 4 waves 2x2; wave tile 64x32. XOR-swizzled LDS,
// global_load_lds width 16. XCD-grouped decode keeps one strip's 8 n-tiles
// on one XCD (A strip reused from that XCD's L2).

#define BKK 64
#define GG1 640   // gemm blocks per dispatch

__device__ __forceinline__ void gemm_body(
    const unsigned short* __restrict__ A, const unsigned short* __restrict__ Bt,
    unsigned short* __restrict__ C, int M, int K, int l) {
    __shared__ char As[128 * BKK * 2] __attribute__((aligned(16)));  // 16 KB
    __shared__ char Bs[64 * BKK * 2]  __attribute__((aligned(16)));  // 8 KB
    const int tid  = threadIdx.x;
    const int lane = tid & 63;
    const int w    = tid >> 6;
    const int wm   = w & 1, wn = w >> 1;
    const int quad = lane >> 4, lq = lane & 15;

    const int xcd   = l & 7;
    const int q     = l >> 3;
    const int strip = (q >> 3) * 8 + xcd;
    const int bm    = strip * 128;
    const int bn    = (q & 7) * 64;

    f32x4 acc[4][2] = {};

    for (int k0 = 0; k0 < K; k0 += BKK) {
        #pragma unroll
        for (int i = 0; i < 4; ++i) {
            int c = i * 256 + tid;
            int r = c >> 3;
            int g = (c & 7) ^ (r & 7);      // XOR swizzle (source-side)
            const char* gpA = (const char*)A + ((size_t)(bm + r) * K + k0) * 2 + (g << 4);
            __builtin_amdgcn_global_load_lds(
                (const __attribute__((address_space(1))) void*)gpA,
                (__attribute__((address_space(3))) void*)(As + c * 16), 16, 0, 0);
        }
        #pragma unroll
        for (int i = 0; i < 2; ++i) {
            int c = i * 256 + tid;
            int r = c >> 3;
            int g = (c & 7) ^ (r & 7);
            const char* gpB = (const char*)Bt + ((size_t)(bn + r) * K + k0) * 2 + (g << 4);
            __builtin_amdgcn_global_load_lds(
                (const __attribute__((address_space(1))) void*)gpB,
                (__attribute__((address_space(3))) void*)(Bs + c * 16), 16, 0, 0);
        }
        __syncthreads();

        #pragma unroll
        for (int s = 0; s < 2; ++s) {
            bf16x8 af[4], bfr[2];
            int g = s * 4 + quad;
            #pragma unroll
            for (int i = 0; i < 4; ++i) {
                int r = wm * 64 + i * 16 + lq;
                af[i] = *(const bf16x8*)(As + r * 128 + ((g ^ (r & 7)) << 4));
            }
            #pragma unroll
            for (int j = 0; j < 2; ++j) {
                int n = wn * 32 + j * 16 + lq;
                bfr[j] = *(const bf16x8*)(Bs + n * 128 + ((g ^ (n & 7)) << 4));
            }
            #pragma unroll
            for (int i = 0; i < 4; ++i)
                #pragma unroll
                for (int j = 0; j < 2; ++j)
                    acc[i][j] = __builtin_amdgcn_mfma_f32_16x16x32_bf16(
                        af[i], bfr[j], acc[i][j], 0, 0, 0);
        }
        __syncthreads();
    }

    // C/D layout: col = lane&15, row = quad*4 + reg
    #pragma unroll
    for (int i = 0; i < 4; ++i) {
        #pragma unroll
        for (int p = 0; p < 4; ++p) {
            int r = bm + wm * 64 + i * 16 + quad * 4 + p;
            if (r < M) {
                #pragma unroll
                for (int j = 0; j < 2; ++j) {
                    int col = bn + wn * 32 + j * 16 + lq;
                    C[(size_t)r * HDIM + col] = f2bf(acc[i][j][p]);
                }
            }
        }
    }
}

// ---------------- dispatch 4: GEMM1 (640 blocks) + CSR fill (625 blocks) ------
// fill needs only scan's row_ptr (done, dispatch 3); GEMM needs cvt+prep (done).
// Merged so fill's serial ~6 us hides under the 30 us GEMM.
__global__ __launch_bounds__(256) void k_gemm1_fill(
    const unsigned short* __restrict__ A, const unsigned short* __restrict__ Bt,
    unsigned short* __restrict__ C, int M, int K,
    const int* __restrict__ ei, const int* __restrict__ row_ptr,
    int* __restrict__ row_cnt, int* __restrict__ col_src) {
    int bx = blockIdx.x;
    if (bx < GG1) { gemm_body(A, Bt, C, M, K, bx); return; }
    int i = (bx - GG1) * 256 + threadIdx.x;
    if (i < NEDGES) {
        int src = ei[i];
        int dst = ei[NEDGES + i];
        int pos = row_ptr[dst] + atomicAdd(&row_cnt[dst], 1);
        col_src[pos] = src;
    }
}

// ---------------- GEMM (layers 2/3) ----------------
__global__ __launch_bounds__(256) void k_gemm_bf16(
    const unsigned short* __restrict__ A, const unsigned short* __restrict__ Bt,
    unsigned short* __restrict__ C, int M, int K) {
    gemm_body(A, Bt, C, M, K, blockIdx.x);
}

// ---------------- aggregation (layers 1/2): bf16 in, fp32 acc, bf16+relu out ----

__global__ void k_agg(const unsigned short* __restrict__ Y, const float* __restrict__ dinv,
                      const int* __restrict__ row_ptr, const int* __restrict__ col_src,
                      const float* __restrict__ bias, unsigned short* __restrict__ Hb) {
    int w = (blockIdx.x * blockDim.x + threadIdx.x) >> 6;
    int lane = threadIdx.x & 63;
    if (w >= MPAD) return;
    unsigned short* hr = Hb + (size_t)w * HDIM + lane * 8;
    if (w >= NNODES) {
        u16x8 z = {0, 0, 0, 0, 0, 0, 0, 0};
        *(u16x8*)hr = z;
        return;
    }
    float di = dinv[w];
    float sw = di * di;
    u16x8 own = *(const u16x8*)(Y + (size_t)w * HDIM + lane * 8);
    float acc[8];
    #pragma unroll
    for (int t = 0; t < 8; ++t) acc[t] = sw * bf2f(own[t]);

    int e0 = row_ptr[w], e1 = row_ptr[w + 1];
    int e = e0;
    for (; e + 4 <= e1; e += 4) {
        int s0 = col_src[e + 0], s1 = col_src[e + 1];
        int s2 = col_src[e + 2], s3 = col_src[e + 3];
        float w0 = di * dinv[s0], w1 = di * dinv[s1];
        float w2 = di * dinv[s2], w3 = di * dinv[s3];
        u16x8 v0 = *(const u16x8*)(Y + (size_t)s0 * HDIM + lane * 8);
        u16x8 v1 = *(const u16x8*)(Y + (size_t)s1 * HDIM + lane * 8);
        u16x8 v2 = *(const u16x8*)(Y + (size_t)s2 * HDIM + lane * 8);
        u16x8 v3 = *(const u16x8*)(Y + (size_t)s3 * HDIM + lane * 8);
        #pragma unroll
        for (int t = 0; t < 8; ++t) {
            acc[t] += w0 * bf2f(v0[t]);
            acc[t] += w1 * bf2f(v1[t]);
            acc[t] += w2 * bf2f(v2[t]);
            acc[t] += w3 * bf2f(v3[t]);
        }
    }
    for (; e < e1; ++e) {
        int s = col_src[e];
        float wg = di * dinv[s];
        u16x8 v = *(const u16x8*)(Y + (size_t)s * HDIM + lane * 8);
        #pragma unroll
        for (int t = 0; t < 8; ++t) acc[t] += wg * bf2f(v[t]);
    }

    float4 b0 = ((const float4*)bias)[lane * 2];
    float4 b1 = ((const float4*)bias)[lane * 2 + 1];
    acc[0] += b0.x; acc[1] += b0.y; acc[2] += b0.z; acc[3] += b0.w;
    acc[4] += b1.x; acc[5] += b1.y; acc[6] += b1.z; acc[7] += b1.w;
    u16x8 o;
    #pragma unroll
    for (int t = 0; t < 8; ++t) o[t] = f2bf(fmaxf(acc[t], 0.0f));
    *(u16x8*)hr = o;
}

// ---------------- agg3 + relu + layer-4 GEMM fused: H stays in registers ------

__global__ void k_agg_g4(const unsigned short* __restrict__ Y, const float* __restrict__ dinv,
                         const int* __restrict__ row_ptr, const int* __restrict__ col_src,
                         const float* __restrict__ b3, const float* __restrict__ W4,
                         float* __restrict__ Y4) {
    int w = (blockIdx.x * blockDim.x + threadIdx.x) >> 6;
    int lane = threadIdx.x & 63;
    if (w >= NNODES) return;
    float di = dinv[w];
    float sw = di * di;
    u16x8 own = *(const u16x8*)(Y + (size_t)w * HDIM + lane * 8);
    float acc[8];
    #pragma unroll
    for (int t = 0; t < 8; ++t) acc[t] = sw * bf2f(own[t]);

    int e0 = row_ptr[w], e1 = row_ptr[w + 1];
    int e = e0;
    for (; e + 4 <= e1; e += 4) {
        int s0 = col_src[e + 0], s1 = col_src[e + 1];
        int s2 = col_src[e + 2], s3 = col_src[e + 3];
        float w0 = di * dinv[s0], w1 = di * dinv[s1];
        float w2 = di * dinv[s2], w3 = di * dinv[s3];
        u16x8 v0 = *(const u16x8*)(Y + (size_t)s0 * HDIM + lane * 8);
        u16x8 v1 = *(const u16x8*)(Y + (size_t)s1 * HDIM + lane * 8);
        u16x8 v2 = *(const u16x8*)(Y + (size_t)s2 * HDIM + lane * 8);
        u16x8 v3 = *(const u16x8*)(Y + (size_t)s3 * HDIM + lane * 8);
        #pragma unroll
        for (int t = 0; t < 8; ++t) {
            acc[t] += w0 * bf2f(v0[t]);
            acc[t] += w1 * bf2f(v1[t]);
            acc[t] += w2 * bf2f(v2[t]);
            acc[t] += w3 * bf2f(v3[t]);
        }
    }
    for (; e < e1; ++e) {
        int s = col_src[e];
        float wg = di * dinv[s];
        u16x8 v = *(const u16x8*)(Y + (size_t)s * HDIM + lane * 8);
        #pragma unroll
        for (int t = 0; t < 8; ++t) acc[t] += wg * bf2f(v[t]);
    }

    float4 b0 = ((const float4*)b3)[lane * 2];
    float4 b1 = ((const float4*)b3)[lane * 2 + 1];
    acc[0] += b0.x; acc[1] += b0.y; acc[2] += b0.z; acc[3] += b0.w;
    acc[4] += b1.x; acc[5] += b1.y; acc[6] += b1.z; acc[7] += b1.w;
    #pragma unroll
    for (int t = 0; t < 8; ++t) acc[t] = fmaxf(acc[t], 0.0f);

    // dot with W4 [512][2] fp32; lane owns k = lane*8 .. lane*8+7
    const float4* wf = (const float4*)W4;
    float4 w0 = wf[lane * 4 + 0];
    float4 w1 = wf[lane * 4 + 1];
    float4 w2 = wf[lane * 4 + 2];
    float4 w3 = wf[lane * 4 + 3];
    float z0 = acc[0]*w0.x + acc[1]*w0.z + acc[2]*w1.x + acc[3]*w1.z
             + acc[4]*w2.x + acc[5]*w2.z + acc[6]*w3.x + acc[7]*w3.z;
    float z1 = acc[0]*w0.y + acc[1]*w0.w + acc[2]*w1.y + acc[3]*w1.w
             + acc[4]*w2.y + acc[5]*w2.w + acc[6]*w3.y + acc[7]*w3.w;
    #pragma unroll
    for (int off = 32; off > 0; off >>= 1) {
        z0 += __shfl_down(z0, off);
        z1 += __shfl_down(z1, off);
    }
    if (lane == 0) {
        Y4[2 * w] = z0;
        Y4[2 * w + 1] = z1;
    }
}

// ---------------- layer-4 aggregation + bias + log_softmax ----------------

__global__ void k_final(const float* __restrict__ Y4, const float* __restrict__ dinv,
                        const int* __restrict__ row_ptr, const int* __restrict__ col_src,
                        const float* __restrict__ b4, float* __restrict__ out, int n) {
    int i = blockIdx.x * blockDim.x + threadIdx.x;
    if (i >= n) return;
    float di = dinv[i];
    float sw = di * di;
    float z0 = sw * Y4[2 * i];
    float z1 = sw * Y4[2 * i + 1];
    int e0 = row_ptr[i], e1 = row_ptr[i + 1];
    for (int e = e0; e < e1; ++e) {
        int s = col_src[e];
        float wgt = di * dinv[s];
        z0 += wgt * Y4[2 * s];
        z1 += wgt * Y4[2 * s + 1];
    }
    z0 += b4[0];
    z1 += b4[1];
    float m = fmaxf(z0, z1);
    float l = m + logf(expf(z0 - m) + expf(z1 - m));
    out[2 * i] = z0 - l;
    out[2 * i + 1] = z1 - l;
}

// ---------------- launch ----------------

extern "C" void kernel_launch(void* const* d_in, const int* in_sizes, int n_in,
                              void* d_out, int out_size, void* d_ws, size_t ws_size,
                              hipStream_t stream) {
    const float* x  = (const float*)d_in[0];
    const int*   ei = (const int*)d_in[1];
    const float* W1 = (const float*)d_in[3];
    const float* b1 = (const float*)d_in[4];
    const float* W2 = (const float*)d_in[5];
    const float* b2 = (const float*)d_in[6];
    const float* W3 = (const float*)d_in[7];
    const float* b3 = (const float*)d_in[8];
    const float* W4 = (const float*)d_in[9];
    const float* b4 = (const float*)d_in[10];
    float* out = (float*)d_out;

    char* ws = (char*)d_ws;
    // workspace layout (bytes, 256-aligned)
    float*          dinv    = (float*)(ws + 0);                  // 40,000
    int*            cnt     = (int*)  (ws + 40960);
    int*            row_cnt = (int*)  (ws + 81920);
    int*            row_ptr = (int*)  (ws + 122880);             // 40,004
    int*            col_src = (int*)  (ws + 163840);             // 640,000
    float*          Y4      = (float*)(ws + 803840);             // 80,000
    unsigned short* xb      = (unsigned short*)(ws + 884224);    // MPAD*K1PAD*2 = 45,875,200
    unsigned short* W1t     = (unsigned short*)(ws + 46759424);  // 2,293,760
    unsigned short* W2t     = (unsigned short*)(ws + 49053184);  // 524,288
    unsigned short* W3t     = (unsigned short*)(ws + 49577472);  // 524,288
    unsigned short* Yb      = (unsigned short*)(ws + 50101760);  // MPAD*512*2 = 10,485,760
    unsigned short* Hb      = (unsigned short*)(ws + 60587520);  // 10,485,760
    // total: 71,073,280 bytes
    if (ws_size < 71073280) return;

    const int agrid = (MPAD * 64) / 256;  // one wave per (padded) node

    // d1: weight transposes + cnt init
    k_prep<<<dim3(14, HDIM), 256, 0, stream>>>(W1, W2, W3, W1t, W2t, W3t, cnt, row_cnt);
    // d2: x->bf16 convert + degree histogram (independent, merged)
    k_cvt_hist<<<MPAD + 625, 256, 0, stream>>>(x, xb, ei, cnt);
    // d3: prefix scan + dinv
    k_scan<<<1, 1024, 0, stream>>>(cnt, row_ptr, dinv, NNODES);
    // d4: layer-1 GEMM + CSR fill (independent, merged)
    k_gemm1_fill<<<GG1 + 625, 256, 0, stream>>>(xb, W1t, Yb, NNODES, K1PAD,
                                                ei, row_ptr, row_cnt, col_src);
    // d5: layer-1 aggregation
    k_agg<<<agrid, 256, 0, stream>>>(Yb, dinv, row_ptr, col_src, b1, Hb);
    // d6/d7: layer 2
    k_gemm_bf16<<<GG1, 256, 0, stream>>>(Hb, W2t, Yb, NNODES, HDIM);
    k_agg<<<agrid, 256, 0, stream>>>(Yb, dinv, row_ptr, col_src, b2, Hb);
    // d8/d9: layer 3 + fused layer-4 GEMM
    k_gemm_bf16<<<GG1, 256, 0, stream>>>(Hb, W3t, Yb, NNODES, HDIM);
    k_agg_g4<<<(NNODES * 64) / 256, 256, 0, stream>>>(Yb, dinv, row_ptr, col_src, b3, W4, Y4);
    // d10: layer-4 aggregation + log_softmax
    k_final<<<40, 256, 0, stream>>>(Y4, dinv, row_ptr, col_src, b4, out, NNODES);
}